// Round 5
// baseline (570.747 us; speedup 1.0000x reference)
//
#include <hip/hip_runtime.h>
#include <hip/hip_bf16.h>
#include <math.h>

// Problem constants
#define D_DIM 128
#define M_CODES 2048
#define BN_TOT 65536           // B*N = 16*4096
#define OUT_LOSS 8388608       // flat offset of loss
#define OUT_PERP 8388609       // flat offset of perp
#define OUT_IDX 8388610        // flat offset of indices
#define MARGIN 2e-3f           // covers ref fp32 noise (~1.6e-5) + bf16-split err

#define QB 32                  // queries per argmin block

// ws byte offsets
#define WS_L2K 0               // float l2k[2048]              (8 KB)
#define WS_WHI 8192            // bf16 whi[2048*128]           (512 KB)
#define WS_WLO 532480          // bf16 wlo[2048*128]           (512 KB)
#define WS_IDX 1056768         // int best_idx[65536]          (256 KB)
#define WS_PART 1318912        // float loss_part[8192]        (32 KB)
#define WS_CNT 1351680         // int counts[2048]             (8 KB)
#define WS_FLAGCNT 1359872     // int flag_count               (pad to 1 KB)
#define WS_FLAGGED 1360896     // int flagged[65536]           (256 KB)

typedef __bf16 bf16x8 __attribute__((ext_vector_type(8)));
typedef __bf16 bf16x4 __attribute__((ext_vector_type(4)));
typedef float f32x4 __attribute__((ext_vector_type(4)));

#define A_STRIDE 136           // bf16 units; 16B-aligned fragment reads

// ---------------------------------------------------------------------------
// Emulated-np ||k||^2: terms rounded to fp32 (w*w), summed in fp64, rounded
// back to fp32 (matches the reference's fp32 sum within ~1 ulp).
// ---------------------------------------------------------------------------
__global__ __launch_bounds__(256) void l2_kernel(const float* __restrict__ w,
                                                 float* __restrict__ l2k) {
  int i = blockIdx.x * 256 + threadIdx.x;
  const float4* p = (const float4*)(w + (size_t)i * D_DIM);
  double s = 0.0;
#pragma unroll
  for (int j = 0; j < 32; ++j) {
    float4 v = p[j];
    s += (double)(v.x * v.x);
    s += (double)(v.y * v.y);
    s += (double)(v.z * v.z);
    s += (double)(v.w * v.w);
  }
  l2k[i] = (float)s;
}

// ---------------------------------------------------------------------------
// Prepack codebook to hi/lo bf16 (row-major [2048][128]); done ONCE so the
// argmin K-loop has zero conversion VALU and half the L2 bytes.
// ---------------------------------------------------------------------------
__global__ __launch_bounds__(256) void pack_w(const float* __restrict__ w,
                                              __bf16* __restrict__ whi,
                                              __bf16* __restrict__ wlo) {
  int fid = blockIdx.x * 256 + threadIdx.x;  // float4 id in [0, 65536)
  float4 v = ((const float4*)w)[fid];
  float f[4] = {v.x, v.y, v.z, v.w};
  bf16x4 h, l;
#pragma unroll
  for (int j = 0; j < 4; ++j) {
    __bf16 hh = (__bf16)f[j];
    h[j] = hh;
    l[j] = (__bf16)(f[j] - (float)hh);
  }
  *(bf16x4*)(whi + (size_t)fid * 4) = h;
  *(bf16x4*)(wlo + (size_t)fid * 4) = l;
}

// merge (ob,os,oi) into (b,s,i): best+second-best with first-index tie-break
__device__ __forceinline__ void merge_bs(float& b, float& s, int& i,
                                         float ob, float os, int oi) {
  if (ob < b) {
    s = fminf(b, os);
    b = ob;
    i = oi;
  } else if (ob > b) {
    s = fminf(s, ob);
  } else {           // tie: gap 0 -> flagged -> fixup resolves exactly
    s = b;
    if (oi < i) i = oi;
  }
}

// ---------------------------------------------------------------------------
// MFMA argmin: dist = l2k - 2*q.k via split-bf16 (hi/lo) 16x16x32 MFMA.
// Block = 256 threads (4 waves), 32 queries x ALL 2048 codes.
// A (queries) staged once in LDS; B fragments stream prepacked from L2.
// Per-lane running (best, second, idx) per (mt,r); one reduction at the end.
// ---------------------------------------------------------------------------
__global__ __launch_bounds__(256, 4) void argmin_mfma(
    const float* __restrict__ x, const __bf16* __restrict__ whi,
    const __bf16* __restrict__ wlo, const float* __restrict__ l2k,
    int* __restrict__ best_idx, int* __restrict__ flag_count,
    int* __restrict__ flagged) {
  __shared__ __bf16 aHi[QB * A_STRIDE];
  __shared__ __bf16 aLo[QB * A_STRIDE];
  __shared__ float redB[4][QB];
  __shared__ float redS[4][QB];
  __shared__ int redI[4][QB];

  const int tid = threadIdx.x;
  const int q0 = blockIdx.x * QB;
  const int wv = tid >> 6;        // wave 0..3
  const int lane = tid & 63;
  const int col = lane & 15;      // MFMA n-index / A m-index
  const int quad = lane >> 4;     // 0..3

  // ---- Stage A tile (32q x 128k), fp32 -> hi/lo bf16, once ----
#pragma unroll
  for (int it = 0; it < 4; ++it) {
    int fid = tid + it * 256;           // float4 id in [0, 1024)
    int q = fid >> 5;
    int k4 = (fid & 31) * 4;
    float4 v = *(const float4*)(x + (size_t)(q0 + q) * D_DIM + k4);
    float f[4] = {v.x, v.y, v.z, v.w};
    int base = q * A_STRIDE + k4;
#pragma unroll
    for (int j = 0; j < 4; ++j) {
      __bf16 h = (__bf16)f[j];
      aHi[base + j] = h;
      aLo[base + j] = (__bf16)(f[j] - (float)h);
    }
  }
  __syncthreads();

  // per-lane running argmin state: query = q0 + 16*mt + 4*quad + r
  float m1[2][4], m2[2][4];
  int bi[2][4];
#pragma unroll
  for (int mt = 0; mt < 2; ++mt)
#pragma unroll
    for (int r = 0; r < 4; ++r) {
      m1[mt][r] = 3.4e38f;
      m2[mt][r] = 3.4e38f;
      bi[mt][r] = 0;
    }

  // ---- Chunk loop: wave wv covers codes chunk*256 + wv*64 + nt*16 + col ----
  for (int ch = 0; ch < 8; ++ch) {
    const int cb = ch * 256 + wv * 64;

    f32x4 acc[2][4];                    // [mt][nt]
#pragma unroll
    for (int mt = 0; mt < 2; ++mt)
#pragma unroll
      for (int nt = 0; nt < 4; ++nt) acc[mt][nt] = (f32x4){0.f, 0.f, 0.f, 0.f};

#pragma unroll
    for (int ks = 0; ks < 4; ++ks) {
      // B fragments: prepacked bf16, single dwordx4 each (L2-hot)
      bf16x8 bh[4], bl[4];
#pragma unroll
      for (int nt = 0; nt < 4; ++nt) {
        size_t off = (size_t)(cb + 16 * nt + col) * D_DIM + 32 * ks + quad * 8;
        bh[nt] = *(const bf16x8*)(whi + off);
        bl[nt] = *(const bf16x8*)(wlo + off);
      }
      // A fragments from LDS
      bf16x8 ah[2], al[2];
#pragma unroll
      for (int mt = 0; mt < 2; ++mt) {
        int off = (16 * mt + col) * A_STRIDE + 32 * ks + quad * 8;
        ah[mt] = *(const bf16x8*)&aHi[off];
        al[mt] = *(const bf16x8*)&aLo[off];
      }
#pragma unroll
      for (int nt = 0; nt < 4; ++nt) {
#pragma unroll
        for (int mt = 0; mt < 2; ++mt) {
          acc[mt][nt] = __builtin_amdgcn_mfma_f32_16x16x32_bf16(
              al[mt], bh[nt], acc[mt][nt], 0, 0, 0);
          acc[mt][nt] = __builtin_amdgcn_mfma_f32_16x16x32_bf16(
              ah[mt], bl[nt], acc[mt][nt], 0, 0, 0);
          acc[mt][nt] = __builtin_amdgcn_mfma_f32_16x16x32_bf16(
              ah[mt], bh[nt], acc[mt][nt], 0, 0, 0);
        }
      }
    }

    // ---- Fold dist into per-lane running state (branchless, no shfl) ----
    // Lane's candidate codes ascend over (ch, nt) -> strict < keeps first.
#pragma unroll
    for (int nt = 0; nt < 4; ++nt) {
      int ci = cb + 16 * nt + col;
      float l2 = l2k[ci];
#pragma unroll
      for (int mt = 0; mt < 2; ++mt) {
#pragma unroll
        for (int r = 0; r < 4; ++r) {
          float dd = fmaf(-2.0f, acc[mt][nt][r], l2);
          bool lt = dd < m1[mt][r];
          m2[mt][r] = lt ? m1[mt][r] : fminf(m2[mt][r], dd);
          bi[mt][r] = lt ? ci : bi[mt][r];
          m1[mt][r] = fminf(m1[mt][r], dd);
        }
      }
    }
  }

  // ---- One cross-lane reduction: 16 lanes (cols) per quad-row ----
#pragma unroll
  for (int mt = 0; mt < 2; ++mt) {
#pragma unroll
    for (int r = 0; r < 4; ++r) {
      float b = m1[mt][r], s = m2[mt][r];
      int i = bi[mt][r];
#pragma unroll
      for (int m = 1; m < 16; m <<= 1) {
        float ob = __shfl_xor(b, m);
        float os = __shfl_xor(s, m);
        int oi = __shfl_xor(i, m);
        merge_bs(b, s, i, ob, os, oi);
      }
      if (col == 0) {
        int qloc = 16 * mt + 4 * quad + r;
        redB[wv][qloc] = b;
        redS[wv][qloc] = s;
        redI[wv][qloc] = i;
      }
    }
  }
  __syncthreads();

  // ---- Final merge across the 4 waves' code partitions ----
  if (tid < QB) {
    float b = 3.4e38f, s = 3.4e38f;
    int i = 0x7fffffff;
#pragma unroll
    for (int w4 = 0; w4 < 4; ++w4)
      merge_bs(b, s, i, redB[w4][tid], redS[w4][tid], redI[w4][tid]);
    best_idx[q0 + tid] = i;
    if (s - b < MARGIN) {
      int pos = atomicAdd(flag_count, 1);
      flagged[pos] = q0 + tid;
    }
  }
}

// ---------------------------------------------------------------------------
// Fixup: for flagged queries, emulate the reference's fp32 computation:
//   dist = fl32( fl32(l2q32 + l2k32[c]) - fl32(2 * fl32(q.k)) )
// q.k exact in fp64 then rounded once to fp32. First-index tie-break.
// ---------------------------------------------------------------------------
__global__ __launch_bounds__(256) void fixup_kernel(const float* __restrict__ x,
                                                    const float* __restrict__ w,
                                                    const float* __restrict__ l2k32,
                                                    const int* __restrict__ flagged,
                                                    const int* __restrict__ flag_count,
                                                    int* __restrict__ best_idx) {
  __shared__ float qs[D_DIM];
  __shared__ float l2q_sh;
  __shared__ float redD[256];
  __shared__ int redI[256];
  const int tid = threadIdx.x;
  const int n = *flag_count;
  for (int f = blockIdx.x; f < n; f += gridDim.x) {
    __syncthreads();
    int q = flagged[f];
    if (tid < D_DIM) qs[tid] = x[(size_t)q * D_DIM + tid];
    __syncthreads();
    if (tid == 0) {
      double s = 0.0;
      for (int d = 0; d < D_DIM; ++d) {
        float t = qs[d] * qs[d];
        s += (double)t;
      }
      l2q_sh = (float)s;
    }
    __syncthreads();
    const float l2q = l2q_sh;
    float bd = 3.4e38f;
    int bi = 0x7fffffff;
    for (int c = tid; c < M_CODES; c += 256) {
      const float4* wr = (const float4*)(w + (size_t)c * D_DIM);
      double s = 0.0;
#pragma unroll
      for (int j = 0; j < 32; ++j) {
        float4 v = wr[j];
        s = fma((double)qs[j * 4 + 0], (double)v.x, s);
        s = fma((double)qs[j * 4 + 1], (double)v.y, s);
        s = fma((double)qs[j * 4 + 2], (double)v.z, s);
        s = fma((double)qs[j * 4 + 3], (double)v.w, s);
      }
      float simf = (float)s;
      float S = l2q + l2k32[c];
      float T = 2.0f * simf;
      float dist = S - T;
      if (dist < bd) { bd = dist; bi = c; }
    }
    redD[tid] = bd;
    redI[tid] = bi;
    __syncthreads();
    for (int off = 128; off; off >>= 1) {
      if (tid < off) {
        float od = redD[tid + off];
        int oi = redI[tid + off];
        if (od < redD[tid] || (od == redD[tid] && oi < redI[tid])) {
          redD[tid] = od;
          redI[tid] = oi;
        }
      }
      __syncthreads();
    }
    if (tid == 0) best_idx[q] = redI[0];
  }
}

// ---------------------------------------------------------------------------
// Gather + straight-through output + loss partials + histogram + indices out
// ---------------------------------------------------------------------------
__global__ __launch_bounds__(256) void epilogue_kernel(const float* __restrict__ x,
                                                       const float* __restrict__ w,
                                                       const int* __restrict__ best_idx,
                                                       float* __restrict__ out,
                                                       float* __restrict__ part,
                                                       int* __restrict__ counts) {
  int gid = blockIdx.x * 256 + threadIdx.x;  // float4 id, 2,097,152 total
  int q = gid >> 5;
  int d4 = gid & 31;
  int idx = best_idx[q];
  float4 xv = ((const float4*)x)[gid];
  float4 wv = ((const float4*)w)[(size_t)idx * 32 + d4];
  float4 o;
  float t0 = wv.x - xv.x; o.x = xv.x + t0; float e0 = o.x - xv.x;
  float t1 = wv.y - xv.y; o.y = xv.y + t1; float e1 = o.y - xv.y;
  float t2 = wv.z - xv.z; o.z = xv.z + t2; float e2 = o.z - xv.z;
  float t3 = wv.w - xv.w; o.w = xv.w + t3; float e3 = o.w - xv.w;
  float ls = e0 * e0 + e1 * e1 + e2 * e2 + e3 * e3;
  ((float4*)out)[gid] = o;

  for (int off = 32; off; off >>= 1) ls += __shfl_down(ls, off);
  __shared__ float red[4];
  if ((threadIdx.x & 63) == 0) red[threadIdx.x >> 6] = ls;
  __syncthreads();
  if (threadIdx.x == 0) part[blockIdx.x] = red[0] + red[1] + red[2] + red[3];

  if (d4 == 0) {
    out[OUT_IDX + q] = (float)idx;
    atomicAdd(&counts[idx], 1);
  }
}

// ---------------------------------------------------------------------------
// Finalize: loss mean + perplexity
// ---------------------------------------------------------------------------
__global__ __launch_bounds__(256) void finalize_kernel(const int* __restrict__ counts,
                                                       const float* __restrict__ part,
                                                       float* __restrict__ out) {
  int tid = threadIdx.x;
  float ls = 0.f;
  for (int i = tid; i < 8192; i += 256) ls += part[i];
  float es = 0.f;
  for (int i = tid; i < M_CODES; i += 256) {
    float p = (float)counts[i] * (1.0f / 65536.0f);
    es += p * logf(p + 1e-10f);
  }
  for (int off = 32; off; off >>= 1) {
    ls += __shfl_down(ls, off);
    es += __shfl_down(es, off);
  }
  __shared__ float redl[4], rede[4];
  if ((tid & 63) == 0) {
    redl[tid >> 6] = ls;
    rede[tid >> 6] = es;
  }
  __syncthreads();
  if (tid == 0) {
    out[OUT_LOSS] = (redl[0] + redl[1] + redl[2] + redl[3]) * (1.0f / 8388608.0f);
    out[OUT_PERP] = expf(-(rede[0] + rede[1] + rede[2] + rede[3]));
  }
}

extern "C" void kernel_launch(void* const* d_in, const int* in_sizes, int n_in,
                              void* d_out, int out_size, void* d_ws, size_t ws_size,
                              hipStream_t stream) {
  const float* x = (const float*)d_in[0];
  const float* w = (const float*)d_in[1];
  float* out = (float*)d_out;
  char* ws = (char*)d_ws;
  float* l2k = (float*)(ws + WS_L2K);
  __bf16* whi = (__bf16*)(ws + WS_WHI);
  __bf16* wlo = (__bf16*)(ws + WS_WLO);
  int* bidx = (int*)(ws + WS_IDX);
  float* part = (float*)(ws + WS_PART);
  int* counts = (int*)(ws + WS_CNT);
  int* flagcnt = (int*)(ws + WS_FLAGCNT);
  int* flagged = (int*)(ws + WS_FLAGGED);

  hipMemsetAsync(counts, 0, M_CODES * sizeof(int), stream);
  hipMemsetAsync(flagcnt, 0, sizeof(int), stream);
  l2_kernel<<<8, 256, 0, stream>>>(w, l2k);
  pack_w<<<256, 256, 0, stream>>>(w, whi, wlo);
  argmin_mfma<<<BN_TOT / QB, 256, 0, stream>>>(x, whi, wlo, l2k, bidx, flagcnt, flagged);
  fixup_kernel<<<256, 256, 0, stream>>>(x, w, l2k, flagged, flagcnt, bidx);
  epilogue_kernel<<<8192, 256, 0, stream>>>(x, w, bidx, out, part, counts);
  finalize_kernel<<<1, 256, 0, stream>>>(counts, part, out);
}

// Round 6
// 400.132 us; speedup vs baseline: 1.4264x; 1.4264x over previous
//
#include <hip/hip_runtime.h>
#include <hip/hip_bf16.h>
#include <math.h>

// Problem constants
#define D_DIM 128
#define M_CODES 2048
#define BN_TOT 65536           // B*N = 16*4096
#define OUT_LOSS 8388608       // flat offset of loss
#define OUT_PERP 8388609       // flat offset of perp
#define OUT_IDX 8388610        // flat offset of indices
#define MARGIN 2e-3f           // covers ref fp32 noise (~1.6e-5) + bf16-split err

#define QB 32                  // queries per argmin block

// ws byte offsets
#define WS_L2K 0               // float l2k[2048]              (8 KB)
#define WS_WHI 8192            // bf16 whi[2048*128]           (512 KB)
#define WS_WLO 532480          // bf16 wlo[2048*128]           (512 KB)
#define WS_IDX 1056768         // int best_idx[65536]          (256 KB)
#define WS_PART 1318912        // float loss_part[8192]        (32 KB)
#define WS_CNT 1351680         // int counts[2048]             (8 KB)
#define WS_FLAGCNT 1359872     // int flag_count               (pad to 1 KB)
#define WS_FLAGGED 1360896     // int flagged[65536]           (256 KB)

typedef __bf16 bf16x8 __attribute__((ext_vector_type(8)));
typedef __bf16 bf16x4 __attribute__((ext_vector_type(4)));
typedef float f32x4 __attribute__((ext_vector_type(4)));

#define A_STRIDE 136           // bf16 units; 16B-aligned fragment reads

// ---------------------------------------------------------------------------
// Emulated-np ||k||^2: terms rounded to fp32 (w*w), summed in fp64, rounded
// back to fp32 (matches the reference's fp32 sum within ~1 ulp).
// ---------------------------------------------------------------------------
__global__ __launch_bounds__(256) void l2_kernel(const float* __restrict__ w,
                                                 float* __restrict__ l2k) {
  int i = blockIdx.x * 256 + threadIdx.x;
  const float4* p = (const float4*)(w + (size_t)i * D_DIM);
  double s = 0.0;
#pragma unroll
  for (int j = 0; j < 32; ++j) {
    float4 v = p[j];
    s += (double)(v.x * v.x);
    s += (double)(v.y * v.y);
    s += (double)(v.z * v.z);
    s += (double)(v.w * v.w);
  }
  l2k[i] = (float)s;
}

// ---------------------------------------------------------------------------
// Prepack codebook to hi/lo bf16 (row-major [2048][128]); done ONCE so the
// argmin K-loop has zero conversion VALU and half the L2 bytes.
// ---------------------------------------------------------------------------
__global__ __launch_bounds__(256) void pack_w(const float* __restrict__ w,
                                              __bf16* __restrict__ whi,
                                              __bf16* __restrict__ wlo) {
  int fid = blockIdx.x * 256 + threadIdx.x;  // float4 id in [0, 65536)
  float4 v = ((const float4*)w)[fid];
  float f[4] = {v.x, v.y, v.z, v.w};
  bf16x4 h, l;
#pragma unroll
  for (int j = 0; j < 4; ++j) {
    __bf16 hh = (__bf16)f[j];
    h[j] = hh;
    l[j] = (__bf16)(f[j] - (float)hh);
  }
  *(bf16x4*)(whi + (size_t)fid * 4) = h;
  *(bf16x4*)(wlo + (size_t)fid * 4) = l;
}

// merge (ob,os,oi) into (b,s,i): best+second-best with first-index tie-break
__device__ __forceinline__ void merge_bs(float& b, float& s, int& i,
                                         float ob, float os, int oi) {
  if (ob < b) {
    s = fminf(b, os);
    b = ob;
    i = oi;
  } else if (ob > b) {
    s = fminf(s, ob);
  } else {           // tie: gap 0 -> flagged -> fixup resolves exactly
    s = b;
    if (oi < i) i = oi;
  }
}

// ---------------------------------------------------------------------------
// MFMA argmin: dist = l2k - 2*q.k via split-bf16 (hi/lo) 16x16x32 MFMA.
// Block = 256 threads (4 waves), 32 queries x ALL 2048 codes.
// A (queries) staged once in LDS; B fragments stream prepacked from L2.
// Per-lane running (best, second, idx) per (mt,r); one reduction at the end.
// __launch_bounds__(256, 2): VGPR cap 256 -> NO SPILLS (r5's (256,4) forced
// a 64-VGPR allocation and 367 MB of scratch writes per dispatch).
// ---------------------------------------------------------------------------
__global__ __launch_bounds__(256, 2) void argmin_mfma(
    const float* __restrict__ x, const __bf16* __restrict__ whi,
    const __bf16* __restrict__ wlo, const float* __restrict__ l2k,
    int* __restrict__ best_idx, int* __restrict__ flag_count,
    int* __restrict__ flagged) {
  __shared__ __bf16 aHi[QB * A_STRIDE];
  __shared__ __bf16 aLo[QB * A_STRIDE];
  __shared__ float redB[4][QB];
  __shared__ float redS[4][QB];
  __shared__ int redI[4][QB];

  const int tid = threadIdx.x;
  const int q0 = blockIdx.x * QB;
  const int wv = tid >> 6;        // wave 0..3
  const int lane = tid & 63;
  const int col = lane & 15;      // MFMA n-index / A m-index
  const int quad = lane >> 4;     // 0..3

  // ---- Stage A tile (32q x 128k), fp32 -> hi/lo bf16, once ----
#pragma unroll
  for (int it = 0; it < 4; ++it) {
    int fid = tid + it * 256;           // float4 id in [0, 1024)
    int q = fid >> 5;
    int k4 = (fid & 31) * 4;
    float4 v = *(const float4*)(x + (size_t)(q0 + q) * D_DIM + k4);
    float f[4] = {v.x, v.y, v.z, v.w};
    int base = q * A_STRIDE + k4;
#pragma unroll
    for (int j = 0; j < 4; ++j) {
      __bf16 h = (__bf16)f[j];
      aHi[base + j] = h;
      aLo[base + j] = (__bf16)(f[j] - (float)h);
    }
  }
  __syncthreads();

  // per-lane running argmin state: query = q0 + 16*mt + 4*quad + r
  float m1[2][4], m2[2][4];
  int bi[2][4];
#pragma unroll
  for (int mt = 0; mt < 2; ++mt)
#pragma unroll
    for (int r = 0; r < 4; ++r) {
      m1[mt][r] = 3.4e38f;
      m2[mt][r] = 3.4e38f;
      bi[mt][r] = 0;
    }

  // ---- Chunk loop: wave wv covers codes chunk*256 + wv*64 + nt*16 + col ----
  for (int ch = 0; ch < 8; ++ch) {
    const int cb = ch * 256 + wv * 64;

    f32x4 acc[2][4];                    // [mt][nt]
#pragma unroll
    for (int mt = 0; mt < 2; ++mt)
#pragma unroll
      for (int nt = 0; nt < 4; ++nt) acc[mt][nt] = (f32x4){0.f, 0.f, 0.f, 0.f};

#pragma unroll
    for (int ks = 0; ks < 4; ++ks) {
      // B fragments: prepacked bf16, single dwordx4 each (L2-hot)
      bf16x8 bh[4], bl[4];
#pragma unroll
      for (int nt = 0; nt < 4; ++nt) {
        size_t off = (size_t)(cb + 16 * nt + col) * D_DIM + 32 * ks + quad * 8;
        bh[nt] = *(const bf16x8*)(whi + off);
        bl[nt] = *(const bf16x8*)(wlo + off);
      }
      // A fragments from LDS
      bf16x8 ah[2], al[2];
#pragma unroll
      for (int mt = 0; mt < 2; ++mt) {
        int off = (16 * mt + col) * A_STRIDE + 32 * ks + quad * 8;
        ah[mt] = *(const bf16x8*)&aHi[off];
        al[mt] = *(const bf16x8*)&aLo[off];
      }
#pragma unroll
      for (int nt = 0; nt < 4; ++nt) {
#pragma unroll
        for (int mt = 0; mt < 2; ++mt) {
          acc[mt][nt] = __builtin_amdgcn_mfma_f32_16x16x32_bf16(
              al[mt], bh[nt], acc[mt][nt], 0, 0, 0);
          acc[mt][nt] = __builtin_amdgcn_mfma_f32_16x16x32_bf16(
              ah[mt], bl[nt], acc[mt][nt], 0, 0, 0);
          acc[mt][nt] = __builtin_amdgcn_mfma_f32_16x16x32_bf16(
              ah[mt], bh[nt], acc[mt][nt], 0, 0, 0);
        }
      }
    }

    // ---- Fold dist into per-lane running state (branchless, no shfl) ----
    // Lane's candidate codes ascend over (ch, nt) -> strict < keeps first.
#pragma unroll
    for (int nt = 0; nt < 4; ++nt) {
      int ci = cb + 16 * nt + col;
      float l2 = l2k[ci];
#pragma unroll
      for (int mt = 0; mt < 2; ++mt) {
#pragma unroll
        for (int r = 0; r < 4; ++r) {
          float dd = fmaf(-2.0f, acc[mt][nt][r], l2);
          bool lt = dd < m1[mt][r];
          m2[mt][r] = lt ? m1[mt][r] : fminf(m2[mt][r], dd);
          bi[mt][r] = lt ? ci : bi[mt][r];
          m1[mt][r] = fminf(m1[mt][r], dd);
        }
      }
    }
  }

  // ---- One cross-lane reduction: 16 lanes (cols) per quad-row ----
#pragma unroll
  for (int mt = 0; mt < 2; ++mt) {
#pragma unroll
    for (int r = 0; r < 4; ++r) {
      float b = m1[mt][r], s = m2[mt][r];
      int i = bi[mt][r];
#pragma unroll
      for (int m = 1; m < 16; m <<= 1) {
        float ob = __shfl_xor(b, m);
        float os = __shfl_xor(s, m);
        int oi = __shfl_xor(i, m);
        merge_bs(b, s, i, ob, os, oi);
      }
      if (col == 0) {
        int qloc = 16 * mt + 4 * quad + r;
        redB[wv][qloc] = b;
        redS[wv][qloc] = s;
        redI[wv][qloc] = i;
      }
    }
  }
  __syncthreads();

  // ---- Final merge across the 4 waves' code partitions ----
  if (tid < QB) {
    float b = 3.4e38f, s = 3.4e38f;
    int i = 0x7fffffff;
#pragma unroll
    for (int w4 = 0; w4 < 4; ++w4)
      merge_bs(b, s, i, redB[w4][tid], redS[w4][tid], redI[w4][tid]);
    best_idx[q0 + tid] = i;
    if (s - b < MARGIN) {
      int pos = atomicAdd(flag_count, 1);
      flagged[pos] = q0 + tid;
    }
  }
}

// ---------------------------------------------------------------------------
// Fixup: for flagged queries, emulate the reference's fp32 computation:
//   dist = fl32( fl32(l2q32 + l2k32[c]) - fl32(2 * fl32(q.k)) )
// q.k exact in fp64 then rounded once to fp32. First-index tie-break.
// ---------------------------------------------------------------------------
__global__ __launch_bounds__(256) void fixup_kernel(const float* __restrict__ x,
                                                    const float* __restrict__ w,
                                                    const float* __restrict__ l2k32,
                                                    const int* __restrict__ flagged,
                                                    const int* __restrict__ flag_count,
                                                    int* __restrict__ best_idx) {
  __shared__ float qs[D_DIM];
  __shared__ float l2q_sh;
  __shared__ float redD[256];
  __shared__ int redI[256];
  const int tid = threadIdx.x;
  const int n = *flag_count;
  for (int f = blockIdx.x; f < n; f += gridDim.x) {
    __syncthreads();
    int q = flagged[f];
    if (tid < D_DIM) qs[tid] = x[(size_t)q * D_DIM + tid];
    __syncthreads();
    if (tid == 0) {
      double s = 0.0;
      for (int d = 0; d < D_DIM; ++d) {
        float t = qs[d] * qs[d];
        s += (double)t;
      }
      l2q_sh = (float)s;
    }
    __syncthreads();
    const float l2q = l2q_sh;
    float bd = 3.4e38f;
    int bi = 0x7fffffff;
    for (int c = tid; c < M_CODES; c += 256) {
      const float4* wr = (const float4*)(w + (size_t)c * D_DIM);
      double s = 0.0;
#pragma unroll
      for (int j = 0; j < 32; ++j) {
        float4 v = wr[j];
        s = fma((double)qs[j * 4 + 0], (double)v.x, s);
        s = fma((double)qs[j * 4 + 1], (double)v.y, s);
        s = fma((double)qs[j * 4 + 2], (double)v.z, s);
        s = fma((double)qs[j * 4 + 3], (double)v.w, s);
      }
      float simf = (float)s;
      float S = l2q + l2k32[c];
      float T = 2.0f * simf;
      float dist = S - T;
      if (dist < bd) { bd = dist; bi = c; }
    }
    redD[tid] = bd;
    redI[tid] = bi;
    __syncthreads();
    for (int off = 128; off; off >>= 1) {
      if (tid < off) {
        float od = redD[tid + off];
        int oi = redI[tid + off];
        if (od < redD[tid] || (od == redD[tid] && oi < redI[tid])) {
          redD[tid] = od;
          redI[tid] = oi;
        }
      }
      __syncthreads();
    }
    if (tid == 0) best_idx[q] = redI[0];
  }
}

// ---------------------------------------------------------------------------
// Gather + straight-through output + loss partials + histogram + indices out
// ---------------------------------------------------------------------------
__global__ __launch_bounds__(256) void epilogue_kernel(const float* __restrict__ x,
                                                       const float* __restrict__ w,
                                                       const int* __restrict__ best_idx,
                                                       float* __restrict__ out,
                                                       float* __restrict__ part,
                                                       int* __restrict__ counts) {
  int gid = blockIdx.x * 256 + threadIdx.x;  // float4 id, 2,097,152 total
  int q = gid >> 5;
  int d4 = gid & 31;
  int idx = best_idx[q];
  float4 xv = ((const float4*)x)[gid];
  float4 wv = ((const float4*)w)[(size_t)idx * 32 + d4];
  float4 o;
  float t0 = wv.x - xv.x; o.x = xv.x + t0; float e0 = o.x - xv.x;
  float t1 = wv.y - xv.y; o.y = xv.y + t1; float e1 = o.y - xv.y;
  float t2 = wv.z - xv.z; o.z = xv.z + t2; float e2 = o.z - xv.z;
  float t3 = wv.w - xv.w; o.w = xv.w + t3; float e3 = o.w - xv.w;
  float ls = e0 * e0 + e1 * e1 + e2 * e2 + e3 * e3;
  ((float4*)out)[gid] = o;

  for (int off = 32; off; off >>= 1) ls += __shfl_down(ls, off);
  __shared__ float red[4];
  if ((threadIdx.x & 63) == 0) red[threadIdx.x >> 6] = ls;
  __syncthreads();
  if (threadIdx.x == 0) part[blockIdx.x] = red[0] + red[1] + red[2] + red[3];

  if (d4 == 0) {
    out[OUT_IDX + q] = (float)idx;
    atomicAdd(&counts[idx], 1);
  }
}

// ---------------------------------------------------------------------------
// Finalize: loss mean + perplexity
// ---------------------------------------------------------------------------
__global__ __launch_bounds__(256) void finalize_kernel(const int* __restrict__ counts,
                                                       const float* __restrict__ part,
                                                       float* __restrict__ out) {
  int tid = threadIdx.x;
  float ls = 0.f;
  for (int i = tid; i < 8192; i += 256) ls += part[i];
  float es = 0.f;
  for (int i = tid; i < M_CODES; i += 256) {
    float p = (float)counts[i] * (1.0f / 65536.0f);
    es += p * logf(p + 1e-10f);
  }
  for (int off = 32; off; off >>= 1) {
    ls += __shfl_down(ls, off);
    es += __shfl_down(es, off);
  }
  __shared__ float redl[4], rede[4];
  if ((tid & 63) == 0) {
    redl[tid >> 6] = ls;
    rede[tid >> 6] = es;
  }
  __syncthreads();
  if (tid == 0) {
    out[OUT_LOSS] = (redl[0] + redl[1] + redl[2] + redl[3]) * (1.0f / 8388608.0f);
    out[OUT_PERP] = expf(-(rede[0] + rede[1] + rede[2] + rede[3]));
  }
}

extern "C" void kernel_launch(void* const* d_in, const int* in_sizes, int n_in,
                              void* d_out, int out_size, void* d_ws, size_t ws_size,
                              hipStream_t stream) {
  const float* x = (const float*)d_in[0];
  const float* w = (const float*)d_in[1];
  float* out = (float*)d_out;
  char* ws = (char*)d_ws;
  float* l2k = (float*)(ws + WS_L2K);
  __bf16* whi = (__bf16*)(ws + WS_WHI);
  __bf16* wlo = (__bf16*)(ws + WS_WLO);
  int* bidx = (int*)(ws + WS_IDX);
  float* part = (float*)(ws + WS_PART);
  int* counts = (int*)(ws + WS_CNT);
  int* flagcnt = (int*)(ws + WS_FLAGCNT);
  int* flagged = (int*)(ws + WS_FLAGGED);

  hipMemsetAsync(counts, 0, M_CODES * sizeof(int), stream);
  hipMemsetAsync(flagcnt, 0, sizeof(int), stream);
  l2_kernel<<<8, 256, 0, stream>>>(w, l2k);
  pack_w<<<256, 256, 0, stream>>>(w, whi, wlo);
  argmin_mfma<<<BN_TOT / QB, 256, 0, stream>>>(x, whi, wlo, l2k, bidx, flagcnt, flagged);
  fixup_kernel<<<256, 256, 0, stream>>>(x, w, l2k, flagged, flagcnt, bidx);
  epilogue_kernel<<<8192, 256, 0, stream>>>(x, w, bidx, out, part, counts);
  finalize_kernel<<<1, 256, 0, stream>>>(counts, part, out);
}

// Round 7
// 279.792 us; speedup vs baseline: 2.0399x; 1.4301x over previous
//
#include <hip/hip_runtime.h>
#include <hip/hip_bf16.h>
#include <math.h>

// Problem constants
#define D_DIM 128
#define M_CODES 2048
#define BN_TOT 65536           // B*N = 16*4096
#define OUT_LOSS 8388608       // flat offset of loss
#define OUT_PERP 8388609       // flat offset of perp
#define OUT_IDX 8388610        // flat offset of indices
#define MARGIN 2e-3f           // covers ref fp32 noise (~1.6e-5) + bf16-split err

#define QB 32                  // queries per argmin block

// ws byte offsets
#define WS_L2K 0               // float l2k[2048]              (8 KB)
#define WS_PHI 8192            // bf16 packed_hi[32768*8]      (512 KB, MFMA-fragment order)
#define WS_PLO 532480          // bf16 packed_lo[32768*8]      (512 KB)
#define WS_IDX 1056768         // int best_idx[65536]          (256 KB)
#define WS_PART 1318912        // float loss_part[8192]        (32 KB)
#define WS_CNT 1351680         // int counts[2048]             (8 KB)
#define WS_FLAGCNT 1359872     // int flag_count               (pad to 1 KB)
#define WS_FLAGGED 1360896     // int flagged[65536]           (256 KB)

typedef __bf16 bf16x8 __attribute__((ext_vector_type(8)));
typedef float f32x4 __attribute__((ext_vector_type(4)));

#define A_STRIDE 136           // bf16 units; 16B-aligned fragment reads

// ---------------------------------------------------------------------------
// Emulated-np ||k||^2: terms rounded to fp32 (w*w), summed in fp64, rounded
// back to fp32 (matches the reference's fp32 sum within ~1 ulp).
// ---------------------------------------------------------------------------
__global__ __launch_bounds__(256) void l2_kernel(const float* __restrict__ w,
                                                 float* __restrict__ l2k) {
  int i = blockIdx.x * 256 + threadIdx.x;
  const float4* p = (const float4*)(w + (size_t)i * D_DIM);
  double s = 0.0;
#pragma unroll
  for (int j = 0; j < 32; ++j) {
    float4 v = p[j];
    s += (double)(v.x * v.x);
    s += (double)(v.y * v.y);
    s += (double)(v.z * v.z);
    s += (double)(v.w * v.w);
  }
  l2k[i] = (float)s;
}

// ---------------------------------------------------------------------------
// Prepack codebook to hi/lo bf16 in MFMA-FRAGMENT ORDER so the argmin B-load
// is wave-uniform-base + lane*16B (perfectly coalesced 1KB/instruction).
// granule gid = ((c64*16 + ks*4 + nt)*64 + lane), lane=(quad*16+col):
//   data = w[code = c64*64 + nt*16 + col][ks*32 + quad*8 .. +8]
// ---------------------------------------------------------------------------
__global__ __launch_bounds__(256) void pack_w_frag(const float* __restrict__ w,
                                                   __bf16* __restrict__ phi,
                                                   __bf16* __restrict__ plo) {
  int gid = blockIdx.x * 256 + threadIdx.x;  // granule id, 32768 total
  int lane = gid & 63;
  int t = gid >> 6;
  int nt = t & 3;
  int ks = (t >> 2) & 3;
  int c64 = t >> 4;                          // 0..31
  int code = c64 * 64 + nt * 16 + (lane & 15);
  int koff = ks * 32 + (lane >> 4) * 8;
  const float* src = w + (size_t)code * D_DIM + koff;
  float4 u = *(const float4*)src;
  float4 v = *(const float4*)(src + 4);
  float f[8] = {u.x, u.y, u.z, u.w, v.x, v.y, v.z, v.w};
  bf16x8 h, l;
#pragma unroll
  for (int j = 0; j < 8; ++j) {
    __bf16 hh = (__bf16)f[j];
    h[j] = hh;
    l[j] = (__bf16)(f[j] - (float)hh);
  }
  *(bf16x8*)(phi + (size_t)gid * 8) = h;
  *(bf16x8*)(plo + (size_t)gid * 8) = l;
}

// merge (ob,os,oi) into (b,s,i): best+second-best with first-index tie-break
__device__ __forceinline__ void merge_bs(float& b, float& s, int& i,
                                         float ob, float os, int oi) {
  if (ob < b) {
    s = fminf(b, os);
    b = ob;
    i = oi;
  } else if (ob > b) {
    s = fminf(s, ob);
  } else {           // tie: gap 0 -> flagged -> fixup resolves exactly
    s = b;
    if (oi < i) i = oi;
  }
}

// ---------------------------------------------------------------------------
// MFMA argmin: dist = l2k - 2*q.k via split-bf16 (hi/lo) 16x16x32 MFMA.
// Block = 256 threads (4 waves), 32 queries x ALL 2048 codes.
// A (queries) staged once in LDS; B streams COALESCED from the
// fragment-packed L2-resident arrays (r6's per-lane 256B-strided gather was
// the 273us wall: 16 discontiguous 64B segments per load instruction).
// __launch_bounds__(256, 2): VGPR cap 256 -> no spills (r5 lesson).
// ---------------------------------------------------------------------------
__global__ __launch_bounds__(256, 2) void argmin_mfma(
    const float* __restrict__ x, const __bf16* __restrict__ phi,
    const __bf16* __restrict__ plo, const float* __restrict__ l2k,
    int* __restrict__ best_idx, int* __restrict__ flag_count,
    int* __restrict__ flagged) {
  __shared__ __bf16 aHi[QB * A_STRIDE];
  __shared__ __bf16 aLo[QB * A_STRIDE];
  __shared__ float redB[4][QB];
  __shared__ float redS[4][QB];
  __shared__ int redI[4][QB];

  const int tid = threadIdx.x;
  const int q0 = blockIdx.x * QB;
  const int wv = tid >> 6;        // wave 0..3
  const int lane = tid & 63;
  const int col = lane & 15;      // MFMA n-index / A m-index
  const int quad = lane >> 4;     // 0..3

  // ---- Stage A tile (32q x 128k), fp32 -> hi/lo bf16, once ----
#pragma unroll
  for (int it = 0; it < 4; ++it) {
    int fid = tid + it * 256;           // float4 id in [0, 1024)
    int q = fid >> 5;
    int k4 = (fid & 31) * 4;
    float4 v = *(const float4*)(x + (size_t)(q0 + q) * D_DIM + k4);
    float f[4] = {v.x, v.y, v.z, v.w};
    int base = q * A_STRIDE + k4;
#pragma unroll
    for (int j = 0; j < 4; ++j) {
      __bf16 h = (__bf16)f[j];
      aHi[base + j] = h;
      aLo[base + j] = (__bf16)(f[j] - (float)h);
    }
  }
  __syncthreads();

  // per-lane running argmin state: query = q0 + 16*mt + 4*quad + r
  float m1[2][4], m2[2][4];
  int bi[2][4];
#pragma unroll
  for (int mt = 0; mt < 2; ++mt)
#pragma unroll
    for (int r = 0; r < 4; ++r) {
      m1[mt][r] = 3.4e38f;
      m2[mt][r] = 3.4e38f;
      bi[mt][r] = 0;
    }

  // ---- Chunk loop: wave wv covers codes ch*256 + wv*64 + nt*16 + col ----
  for (int ch = 0; ch < 8; ++ch) {
    const int cb = ch * 256 + wv * 64;
    const int cb64 = ch * 4 + wv;       // cb / 64

    f32x4 acc[2][4];                    // [mt][nt]
#pragma unroll
    for (int mt = 0; mt < 2; ++mt)
#pragma unroll
      for (int nt = 0; nt < 4; ++nt) acc[mt][nt] = (f32x4){0.f, 0.f, 0.f, 0.f};

#pragma unroll
    for (int ks = 0; ks < 4; ++ks) {
      // B fragments: coalesced stream (uniform base + lane*16B), L2-hot
      bf16x8 bh[4], bl[4];
#pragma unroll
      for (int nt = 0; nt < 4; ++nt) {
        size_t g = (((size_t)cb64 * 16) + ks * 4 + nt) * 64 + lane;
        bh[nt] = *(const bf16x8*)(phi + g * 8);
        bl[nt] = *(const bf16x8*)(plo + g * 8);
      }
      // A fragments from LDS
      bf16x8 ah[2], al[2];
#pragma unroll
      for (int mt = 0; mt < 2; ++mt) {
        int off = (16 * mt + col) * A_STRIDE + 32 * ks + quad * 8;
        ah[mt] = *(const bf16x8*)&aHi[off];
        al[mt] = *(const bf16x8*)&aLo[off];
      }
#pragma unroll
      for (int nt = 0; nt < 4; ++nt) {
#pragma unroll
        for (int mt = 0; mt < 2; ++mt) {
          acc[mt][nt] = __builtin_amdgcn_mfma_f32_16x16x32_bf16(
              al[mt], bh[nt], acc[mt][nt], 0, 0, 0);
          acc[mt][nt] = __builtin_amdgcn_mfma_f32_16x16x32_bf16(
              ah[mt], bl[nt], acc[mt][nt], 0, 0, 0);
          acc[mt][nt] = __builtin_amdgcn_mfma_f32_16x16x32_bf16(
              ah[mt], bh[nt], acc[mt][nt], 0, 0, 0);
        }
      }
    }

    // ---- Fold dist into per-lane running state (branchless, no shfl) ----
    // Lane's candidate codes ascend over (ch, nt) -> strict < keeps first.
#pragma unroll
    for (int nt = 0; nt < 4; ++nt) {
      int ci = cb + 16 * nt + col;
      float l2 = l2k[ci];
#pragma unroll
      for (int mt = 0; mt < 2; ++mt) {
#pragma unroll
        for (int r = 0; r < 4; ++r) {
          float dd = fmaf(-2.0f, acc[mt][nt][r], l2);
          bool lt = dd < m1[mt][r];
          m2[mt][r] = lt ? m1[mt][r] : fminf(m2[mt][r], dd);
          bi[mt][r] = lt ? ci : bi[mt][r];
          m1[mt][r] = fminf(m1[mt][r], dd);
        }
      }
    }
  }

  // ---- One cross-lane reduction: 16 lanes (cols) per quad-row ----
#pragma unroll
  for (int mt = 0; mt < 2; ++mt) {
#pragma unroll
    for (int r = 0; r < 4; ++r) {
      float b = m1[mt][r], s = m2[mt][r];
      int i = bi[mt][r];
#pragma unroll
      for (int m = 1; m < 16; m <<= 1) {
        float ob = __shfl_xor(b, m);
        float os = __shfl_xor(s, m);
        int oi = __shfl_xor(i, m);
        merge_bs(b, s, i, ob, os, oi);
      }
      if (col == 0) {
        int qloc = 16 * mt + 4 * quad + r;
        redB[wv][qloc] = b;
        redS[wv][qloc] = s;
        redI[wv][qloc] = i;
      }
    }
  }
  __syncthreads();

  // ---- Final merge across the 4 waves' code partitions ----
  if (tid < QB) {
    float b = 3.4e38f, s = 3.4e38f;
    int i = 0x7fffffff;
#pragma unroll
    for (int w4 = 0; w4 < 4; ++w4)
      merge_bs(b, s, i, redB[w4][tid], redS[w4][tid], redI[w4][tid]);
    best_idx[q0 + tid] = i;
    if (s - b < MARGIN) {
      int pos = atomicAdd(flag_count, 1);
      flagged[pos] = q0 + tid;
    }
  }
}

// ---------------------------------------------------------------------------
// Fixup: for flagged queries, emulate the reference's fp32 computation:
//   dist = fl32( fl32(l2q32 + l2k32[c]) - fl32(2 * fl32(q.k)) )
// q.k exact in fp64 then rounded once to fp32. First-index tie-break.
// ---------------------------------------------------------------------------
__global__ __launch_bounds__(256) void fixup_kernel(const float* __restrict__ x,
                                                    const float* __restrict__ w,
                                                    const float* __restrict__ l2k32,
                                                    const int* __restrict__ flagged,
                                                    const int* __restrict__ flag_count,
                                                    int* __restrict__ best_idx) {
  __shared__ float qs[D_DIM];
  __shared__ float l2q_sh;
  __shared__ float redD[256];
  __shared__ int redI[256];
  const int tid = threadIdx.x;
  const int n = *flag_count;
  for (int f = blockIdx.x; f < n; f += gridDim.x) {
    __syncthreads();
    int q = flagged[f];
    if (tid < D_DIM) qs[tid] = x[(size_t)q * D_DIM + tid];
    __syncthreads();
    if (tid == 0) {
      double s = 0.0;
      for (int d = 0; d < D_DIM; ++d) {
        float t = qs[d] * qs[d];
        s += (double)t;
      }
      l2q_sh = (float)s;
    }
    __syncthreads();
    const float l2q = l2q_sh;
    float bd = 3.4e38f;
    int bi = 0x7fffffff;
    for (int c = tid; c < M_CODES; c += 256) {
      const float4* wr = (const float4*)(w + (size_t)c * D_DIM);
      double s = 0.0;
#pragma unroll
      for (int j = 0; j < 32; ++j) {
        float4 v = wr[j];
        s = fma((double)qs[j * 4 + 0], (double)v.x, s);
        s = fma((double)qs[j * 4 + 1], (double)v.y, s);
        s = fma((double)qs[j * 4 + 2], (double)v.z, s);
        s = fma((double)qs[j * 4 + 3], (double)v.w, s);
      }
      float simf = (float)s;
      float S = l2q + l2k32[c];
      float T = 2.0f * simf;
      float dist = S - T;
      if (dist < bd) { bd = dist; bi = c; }
    }
    redD[tid] = bd;
    redI[tid] = bi;
    __syncthreads();
    for (int off = 128; off; off >>= 1) {
      if (tid < off) {
        float od = redD[tid + off];
        int oi = redI[tid + off];
        if (od < redD[tid] || (od == redD[tid] && oi < redI[tid])) {
          redD[tid] = od;
          redI[tid] = oi;
        }
      }
      __syncthreads();
    }
    if (tid == 0) best_idx[q] = redI[0];
  }
}

// ---------------------------------------------------------------------------
// Gather + straight-through output + loss partials + histogram + indices out
// ---------------------------------------------------------------------------
__global__ __launch_bounds__(256) void epilogue_kernel(const float* __restrict__ x,
                                                       const float* __restrict__ w,
                                                       const int* __restrict__ best_idx,
                                                       float* __restrict__ out,
                                                       float* __restrict__ part,
                                                       int* __restrict__ counts) {
  int gid = blockIdx.x * 256 + threadIdx.x;  // float4 id, 2,097,152 total
  int q = gid >> 5;
  int d4 = gid & 31;
  int idx = best_idx[q];
  float4 xv = ((const float4*)x)[gid];
  float4 wv = ((const float4*)w)[(size_t)idx * 32 + d4];
  float4 o;
  float t0 = wv.x - xv.x; o.x = xv.x + t0; float e0 = o.x - xv.x;
  float t1 = wv.y - xv.y; o.y = xv.y + t1; float e1 = o.y - xv.y;
  float t2 = wv.z - xv.z; o.z = xv.z + t2; float e2 = o.z - xv.z;
  float t3 = wv.w - xv.w; o.w = xv.w + t3; float e3 = o.w - xv.w;
  float ls = e0 * e0 + e1 * e1 + e2 * e2 + e3 * e3;
  ((float4*)out)[gid] = o;

  for (int off = 32; off; off >>= 1) ls += __shfl_down(ls, off);
  __shared__ float red[4];
  if ((threadIdx.x & 63) == 0) red[threadIdx.x >> 6] = ls;
  __syncthreads();
  if (threadIdx.x == 0) part[blockIdx.x] = red[0] + red[1] + red[2] + red[3];

  if (d4 == 0) {
    out[OUT_IDX + q] = (float)idx;
    atomicAdd(&counts[idx], 1);
  }
}

// ---------------------------------------------------------------------------
// Finalize: loss mean + perplexity
// ---------------------------------------------------------------------------
__global__ __launch_bounds__(256) void finalize_kernel(const int* __restrict__ counts,
                                                       const float* __restrict__ part,
                                                       float* __restrict__ out) {
  int tid = threadIdx.x;
  float ls = 0.f;
  for (int i = tid; i < 8192; i += 256) ls += part[i];
  float es = 0.f;
  for (int i = tid; i < M_CODES; i += 256) {
    float p = (float)counts[i] * (1.0f / 65536.0f);
    es += p * logf(p + 1e-10f);
  }
  for (int off = 32; off; off >>= 1) {
    ls += __shfl_down(ls, off);
    es += __shfl_down(es, off);
  }
  __shared__ float redl[4], rede[4];
  if ((tid & 63) == 0) {
    redl[tid >> 6] = ls;
    rede[tid >> 6] = es;
  }
  __syncthreads();
  if (tid == 0) {
    out[OUT_LOSS] = (redl[0] + redl[1] + redl[2] + redl[3]) * (1.0f / 8388608.0f);
    out[OUT_PERP] = expf(-(rede[0] + rede[1] + rede[2] + rede[3]));
  }
}

extern "C" void kernel_launch(void* const* d_in, const int* in_sizes, int n_in,
                              void* d_out, int out_size, void* d_ws, size_t ws_size,
                              hipStream_t stream) {
  const float* x = (const float*)d_in[0];
  const float* w = (const float*)d_in[1];
  float* out = (float*)d_out;
  char* ws = (char*)d_ws;
  float* l2k = (float*)(ws + WS_L2K);
  __bf16* phi = (__bf16*)(ws + WS_PHI);
  __bf16* plo = (__bf16*)(ws + WS_PLO);
  int* bidx = (int*)(ws + WS_IDX);
  float* part = (float*)(ws + WS_PART);
  int* counts = (int*)(ws + WS_CNT);
  int* flagcnt = (int*)(ws + WS_FLAGCNT);
  int* flagged = (int*)(ws + WS_FLAGGED);

  hipMemsetAsync(counts, 0, M_CODES * sizeof(int), stream);
  hipMemsetAsync(flagcnt, 0, sizeof(int), stream);
  l2_kernel<<<8, 256, 0, stream>>>(w, l2k);
  pack_w_frag<<<128, 256, 0, stream>>>(w, phi, plo);
  argmin_mfma<<<BN_TOT / QB, 256, 0, stream>>>(x, phi, plo, l2k, bidx, flagcnt, flagged);
  fixup_kernel<<<256, 256, 0, stream>>>(x, w, l2k, flagged, flagcnt, bidx);
  epilogue_kernel<<<8192, 256, 0, stream>>>(x, w, bidx, out, part, counts);
  finalize_kernel<<<1, 256, 0, stream>>>(counts, part, out);
}

// Round 8
// 276.909 us; speedup vs baseline: 2.0611x; 1.0104x over previous
//
#include <hip/hip_runtime.h>
#include <hip/hip_bf16.h>
#include <math.h>

// Problem constants
#define D_DIM 128
#define M_CODES 2048
#define BN_TOT 65536           // B*N = 16*4096
#define OUT_LOSS 8388608       // flat offset of loss
#define OUT_PERP 8388609       // flat offset of perp
#define OUT_IDX 8388610        // flat offset of indices
#define MARGIN 2e-3f           // covers ref fp32 noise (~1.6e-5) + bf16-split err

#define QB 32                  // queries per argmin block

// ws byte offsets
#define WS_L2K 0               // float l2k[2048]              (8 KB)
#define WS_PHI 8192            // bf16 packed_hi[32768*8]      (512 KB, MFMA-fragment order)
#define WS_PLO 532480          // bf16 packed_lo[32768*8]      (512 KB)
#define WS_IDX 1056768         // int best_idx[65536]          (256 KB)
#define WS_PART 1318912        // float loss_part[8192]        (32 KB)
#define WS_CNT 1351680         // int counts[2048]             (8 KB)
#define WS_FLAGCNT 1359872     // int flag_count               (pad to 1 KB)
#define WS_FLAGGED 1360896     // int flagged[65536]           (256 KB)

typedef __bf16 bf16x8 __attribute__((ext_vector_type(8)));
typedef float f32x4 __attribute__((ext_vector_type(4)));

#define A_STRIDE 136           // bf16 units; 16B-aligned fragment reads

// ---------------------------------------------------------------------------
// Emulated-np ||k||^2: terms rounded to fp32 (w*w), summed in fp64, rounded
// back to fp32 (matches the reference's fp32 sum within ~1 ulp).
// ---------------------------------------------------------------------------
__global__ __launch_bounds__(256) void l2_kernel(const float* __restrict__ w,
                                                 float* __restrict__ l2k) {
  int i = blockIdx.x * 256 + threadIdx.x;
  const float4* p = (const float4*)(w + (size_t)i * D_DIM);
  double s = 0.0;
#pragma unroll
  for (int j = 0; j < 32; ++j) {
    float4 v = p[j];
    s += (double)(v.x * v.x);
    s += (double)(v.y * v.y);
    s += (double)(v.z * v.z);
    s += (double)(v.w * v.w);
  }
  l2k[i] = (float)s;
}

// ---------------------------------------------------------------------------
// Prepack codebook to hi/lo bf16 in MFMA-FRAGMENT ORDER so the argmin B-load
// is wave-uniform-base + lane*16B (perfectly coalesced 1KB/instruction).
// granule gid = ((c64*16 + ks*4 + nt)*64 + lane), lane=(quad*16+col):
//   data = w[code = c64*64 + nt*16 + col][ks*32 + quad*8 .. +8]
// ---------------------------------------------------------------------------
__global__ __launch_bounds__(256) void pack_w_frag(const float* __restrict__ w,
                                                   __bf16* __restrict__ phi,
                                                   __bf16* __restrict__ plo) {
  int gid = blockIdx.x * 256 + threadIdx.x;  // granule id, 32768 total
  int lane = gid & 63;
  int t = gid >> 6;
  int nt = t & 3;
  int ks = (t >> 2) & 3;
  int c64 = t >> 4;                          // 0..31
  int code = c64 * 64 + nt * 16 + (lane & 15);
  int koff = ks * 32 + (lane >> 4) * 8;
  const float* src = w + (size_t)code * D_DIM + koff;
  float4 u = *(const float4*)src;
  float4 v = *(const float4*)(src + 4);
  float f[8] = {u.x, u.y, u.z, u.w, v.x, v.y, v.z, v.w};
  bf16x8 h, l;
#pragma unroll
  for (int j = 0; j < 8; ++j) {
    __bf16 hh = (__bf16)f[j];
    h[j] = hh;
    l[j] = (__bf16)(f[j] - (float)hh);
  }
  *(bf16x8*)(phi + (size_t)gid * 8) = h;
  *(bf16x8*)(plo + (size_t)gid * 8) = l;
}

// merge (ob,os,oi) into (b,s,i): best+second-best with first-index tie-break
__device__ __forceinline__ void merge_bs(float& b, float& s, int& i,
                                         float ob, float os, int oi) {
  if (ob < b) {
    s = fminf(b, os);
    b = ob;
    i = oi;
  } else if (ob > b) {
    s = fminf(s, ob);
  } else {           // tie: gap 0 -> flagged -> fixup resolves exactly
    s = b;
    if (oi < i) i = oi;
  }
}

// ---------------------------------------------------------------------------
// MFMA argmin: dist = l2k - 2*q.k via split-bf16 (hi/lo) 16x16x32 MFMA.
// Block = 256 threads (4 waves), 32 queries x ALL 2048 codes.
// A (queries) staged once in LDS; B streams coalesced from fragment-packed
// L2-resident arrays. ALL 32 B-granules of a chunk are loaded into live
// register arrays BEFORE the MFMA loop: r7's VGPR_Count=112 allowed only
// ~5 outstanding loads -> 70% stall (MfmaUtil 29%). Forcing ~128 load-dest
// VGPRs (launch_bounds(256,1) lifts the cap; explicit liveness forces the
// allocation) keeps the whole chunk's B in flight under the MFMA shadow.
// ---------------------------------------------------------------------------
__global__ __launch_bounds__(256, 1) void argmin_mfma(
    const float* __restrict__ x, const __bf16* __restrict__ phi,
    const __bf16* __restrict__ plo, const float* __restrict__ l2k,
    int* __restrict__ best_idx, int* __restrict__ flag_count,
    int* __restrict__ flagged) {
  __shared__ __bf16 aHi[QB * A_STRIDE];
  __shared__ __bf16 aLo[QB * A_STRIDE];
  __shared__ float redB[4][QB];
  __shared__ float redS[4][QB];
  __shared__ int redI[4][QB];

  const int tid = threadIdx.x;
  const int q0 = blockIdx.x * QB;
  const int wv = tid >> 6;        // wave 0..3
  const int lane = tid & 63;
  const int col = lane & 15;      // MFMA n-index / A m-index
  const int quad = lane >> 4;     // 0..3

  // ---- Stage A tile (32q x 128k), fp32 -> hi/lo bf16, once ----
#pragma unroll
  for (int it = 0; it < 4; ++it) {
    int fid = tid + it * 256;           // float4 id in [0, 1024)
    int q = fid >> 5;
    int k4 = (fid & 31) * 4;
    float4 v = *(const float4*)(x + (size_t)(q0 + q) * D_DIM + k4);
    float f[4] = {v.x, v.y, v.z, v.w};
    int base = q * A_STRIDE + k4;
#pragma unroll
    for (int j = 0; j < 4; ++j) {
      __bf16 h = (__bf16)f[j];
      aHi[base + j] = h;
      aLo[base + j] = (__bf16)(f[j] - (float)h);
    }
  }
  __syncthreads();

  // per-lane running argmin state: query = q0 + 16*mt + 4*quad + r
  float m1[2][4], m2[2][4];
  int bi[2][4];
#pragma unroll
  for (int mt = 0; mt < 2; ++mt)
#pragma unroll
    for (int r = 0; r < 4; ++r) {
      m1[mt][r] = 3.4e38f;
      m2[mt][r] = 3.4e38f;
      bi[mt][r] = 0;
    }

  // ---- Chunk loop: wave wv covers codes ch*256 + wv*64 + nt*16 + col ----
  for (int ch = 0; ch < 8; ++ch) {
    const int cb = ch * 256 + wv * 64;
    const int cb64 = ch * 4 + wv;       // cb / 64

    // Load the ENTIRE chunk's B fragments first (32 dwordx4, all in flight).
    bf16x8 bh[4][4], bl[4][4];          // [ks][nt] -> 128 VGPRs live
#pragma unroll
    for (int ks = 0; ks < 4; ++ks) {
#pragma unroll
      for (int nt = 0; nt < 4; ++nt) {
        size_t g = (((size_t)cb64 * 16) + ks * 4 + nt) * 64 + lane;
        bh[ks][nt] = *(const bf16x8*)(phi + g * 8);
        bl[ks][nt] = *(const bf16x8*)(plo + g * 8);
      }
    }

    f32x4 acc[2][4];                    // [mt][nt]
#pragma unroll
    for (int mt = 0; mt < 2; ++mt)
#pragma unroll
      for (int nt = 0; nt < 4; ++nt) acc[mt][nt] = (f32x4){0.f, 0.f, 0.f, 0.f};

#pragma unroll
    for (int ks = 0; ks < 4; ++ks) {
      // A fragments from LDS
      bf16x8 ah[2], al[2];
#pragma unroll
      for (int mt = 0; mt < 2; ++mt) {
        int off = (16 * mt + col) * A_STRIDE + 32 * ks + quad * 8;
        ah[mt] = *(const bf16x8*)&aHi[off];
        al[mt] = *(const bf16x8*)&aLo[off];
      }
#pragma unroll
      for (int nt = 0; nt < 4; ++nt) {
#pragma unroll
        for (int mt = 0; mt < 2; ++mt) {
          acc[mt][nt] = __builtin_amdgcn_mfma_f32_16x16x32_bf16(
              al[mt], bh[ks][nt], acc[mt][nt], 0, 0, 0);
          acc[mt][nt] = __builtin_amdgcn_mfma_f32_16x16x32_bf16(
              ah[mt], bl[ks][nt], acc[mt][nt], 0, 0, 0);
          acc[mt][nt] = __builtin_amdgcn_mfma_f32_16x16x32_bf16(
              ah[mt], bh[ks][nt], acc[mt][nt], 0, 0, 0);
        }
      }
    }

    // ---- Fold dist into per-lane running state (branchless, no shfl) ----
    // Lane's candidate codes ascend over (ch, nt) -> strict < keeps first.
#pragma unroll
    for (int nt = 0; nt < 4; ++nt) {
      int ci = cb + 16 * nt + col;
      float l2 = l2k[ci];
#pragma unroll
      for (int mt = 0; mt < 2; ++mt) {
#pragma unroll
        for (int r = 0; r < 4; ++r) {
          float dd = fmaf(-2.0f, acc[mt][nt][r], l2);
          bool lt = dd < m1[mt][r];
          m2[mt][r] = lt ? m1[mt][r] : fminf(m2[mt][r], dd);
          bi[mt][r] = lt ? ci : bi[mt][r];
          m1[mt][r] = fminf(m1[mt][r], dd);
        }
      }
    }
  }

  // ---- One cross-lane reduction: 16 lanes (cols) per quad-row ----
#pragma unroll
  for (int mt = 0; mt < 2; ++mt) {
#pragma unroll
    for (int r = 0; r < 4; ++r) {
      float b = m1[mt][r], s = m2[mt][r];
      int i = bi[mt][r];
#pragma unroll
      for (int m = 1; m < 16; m <<= 1) {
        float ob = __shfl_xor(b, m);
        float os = __shfl_xor(s, m);
        int oi = __shfl_xor(i, m);
        merge_bs(b, s, i, ob, os, oi);
      }
      if (col == 0) {
        int qloc = 16 * mt + 4 * quad + r;
        redB[wv][qloc] = b;
        redS[wv][qloc] = s;
        redI[wv][qloc] = i;
      }
    }
  }
  __syncthreads();

  // ---- Final merge across the 4 waves' code partitions ----
  if (tid < QB) {
    float b = 3.4e38f, s = 3.4e38f;
    int i = 0x7fffffff;
#pragma unroll
    for (int w4 = 0; w4 < 4; ++w4)
      merge_bs(b, s, i, redB[w4][tid], redS[w4][tid], redI[w4][tid]);
    best_idx[q0 + tid] = i;
    if (s - b < MARGIN) {
      int pos = atomicAdd(flag_count, 1);
      flagged[pos] = q0 + tid;
    }
  }
}

// ---------------------------------------------------------------------------
// Fixup: for flagged queries, emulate the reference's fp32 computation:
//   dist = fl32( fl32(l2q32 + l2k32[c]) - fl32(2 * fl32(q.k)) )
// q.k exact in fp64 then rounded once to fp32. First-index tie-break.
// ---------------------------------------------------------------------------
__global__ __launch_bounds__(256) void fixup_kernel(const float* __restrict__ x,
                                                    const float* __restrict__ w,
                                                    const float* __restrict__ l2k32,
                                                    const int* __restrict__ flagged,
                                                    const int* __restrict__ flag_count,
                                                    int* __restrict__ best_idx) {
  __shared__ float qs[D_DIM];
  __shared__ float l2q_sh;
  __shared__ float redD[256];
  __shared__ int redI[256];
  const int tid = threadIdx.x;
  const int n = *flag_count;
  for (int f = blockIdx.x; f < n; f += gridDim.x) {
    __syncthreads();
    int q = flagged[f];
    if (tid < D_DIM) qs[tid] = x[(size_t)q * D_DIM + tid];
    __syncthreads();
    if (tid == 0) {
      double s = 0.0;
      for (int d = 0; d < D_DIM; ++d) {
        float t = qs[d] * qs[d];
        s += (double)t;
      }
      l2q_sh = (float)s;
    }
    __syncthreads();
    const float l2q = l2q_sh;
    float bd = 3.4e38f;
    int bi = 0x7fffffff;
    for (int c = tid; c < M_CODES; c += 256) {
      const float4* wr = (const float4*)(w + (size_t)c * D_DIM);
      double s = 0.0;
#pragma unroll
      for (int j = 0; j < 32; ++j) {
        float4 v = wr[j];
        s = fma((double)qs[j * 4 + 0], (double)v.x, s);
        s = fma((double)qs[j * 4 + 1], (double)v.y, s);
        s = fma((double)qs[j * 4 + 2], (double)v.z, s);
        s = fma((double)qs[j * 4 + 3], (double)v.w, s);
      }
      float simf = (float)s;
      float S = l2q + l2k32[c];
      float T = 2.0f * simf;
      float dist = S - T;
      if (dist < bd) { bd = dist; bi = c; }
    }
    redD[tid] = bd;
    redI[tid] = bi;
    __syncthreads();
    for (int off = 128; off; off >>= 1) {
      if (tid < off) {
        float od = redD[tid + off];
        int oi = redI[tid + off];
        if (od < redD[tid] || (od == redD[tid] && oi < redI[tid])) {
          redD[tid] = od;
          redI[tid] = oi;
        }
      }
      __syncthreads();
    }
    if (tid == 0) best_idx[q] = redI[0];
  }
}

// ---------------------------------------------------------------------------
// Gather + straight-through output + loss partials + histogram + indices out
// ---------------------------------------------------------------------------
__global__ __launch_bounds__(256) void epilogue_kernel(const float* __restrict__ x,
                                                       const float* __restrict__ w,
                                                       const int* __restrict__ best_idx,
                                                       float* __restrict__ out,
                                                       float* __restrict__ part,
                                                       int* __restrict__ counts) {
  int gid = blockIdx.x * 256 + threadIdx.x;  // float4 id, 2,097,152 total
  int q = gid >> 5;
  int d4 = gid & 31;
  int idx = best_idx[q];
  float4 xv = ((const float4*)x)[gid];
  float4 wv = ((const float4*)w)[(size_t)idx * 32 + d4];
  float4 o;
  float t0 = wv.x - xv.x; o.x = xv.x + t0; float e0 = o.x - xv.x;
  float t1 = wv.y - xv.y; o.y = xv.y + t1; float e1 = o.y - xv.y;
  float t2 = wv.z - xv.z; o.z = xv.z + t2; float e2 = o.z - xv.z;
  float t3 = wv.w - xv.w; o.w = xv.w + t3; float e3 = o.w - xv.w;
  float ls = e0 * e0 + e1 * e1 + e2 * e2 + e3 * e3;
  ((float4*)out)[gid] = o;

  for (int off = 32; off; off >>= 1) ls += __shfl_down(ls, off);
  __shared__ float red[4];
  if ((threadIdx.x & 63) == 0) red[threadIdx.x >> 6] = ls;
  __syncthreads();
  if (threadIdx.x == 0) part[blockIdx.x] = red[0] + red[1] + red[2] + red[3];

  if (d4 == 0) {
    out[OUT_IDX + q] = (float)idx;
    atomicAdd(&counts[idx], 1);
  }
}

// ---------------------------------------------------------------------------
// Finalize: loss mean + perplexity
// ---------------------------------------------------------------------------
__global__ __launch_bounds__(256) void finalize_kernel(const int* __restrict__ counts,
                                                       const float* __restrict__ part,
                                                       float* __restrict__ out) {
  int tid = threadIdx.x;
  float ls = 0.f;
  for (int i = tid; i < 8192; i += 256) ls += part[i];
  float es = 0.f;
  for (int i = tid; i < M_CODES; i += 256) {
    float p = (float)counts[i] * (1.0f / 65536.0f);
    es += p * logf(p + 1e-10f);
  }
  for (int off = 32; off; off >>= 1) {
    ls += __shfl_down(ls, off);
    es += __shfl_down(es, off);
  }
  __shared__ float redl[4], rede[4];
  if ((tid & 63) == 0) {
    redl[tid >> 6] = ls;
    rede[tid >> 6] = es;
  }
  __syncthreads();
  if (tid == 0) {
    out[OUT_LOSS] = (redl[0] + redl[1] + redl[2] + redl[3]) * (1.0f / 8388608.0f);
    out[OUT_PERP] = expf(-(rede[0] + rede[1] + rede[2] + rede[3]));
  }
}

extern "C" void kernel_launch(void* const* d_in, const int* in_sizes, int n_in,
                              void* d_out, int out_size, void* d_ws, size_t ws_size,
                              hipStream_t stream) {
  const float* x = (const float*)d_in[0];
  const float* w = (const float*)d_in[1];
  float* out = (float*)d_out;
  char* ws = (char*)d_ws;
  float* l2k = (float*)(ws + WS_L2K);
  __bf16* phi = (__bf16*)(ws + WS_PHI);
  __bf16* plo = (__bf16*)(ws + WS_PLO);
  int* bidx = (int*)(ws + WS_IDX);
  float* part = (float*)(ws + WS_PART);
  int* counts = (int*)(ws + WS_CNT);
  int* flagcnt = (int*)(ws + WS_FLAGCNT);
  int* flagged = (int*)(ws + WS_FLAGGED);

  hipMemsetAsync(counts, 0, M_CODES * sizeof(int), stream);
  hipMemsetAsync(flagcnt, 0, sizeof(int), stream);
  l2_kernel<<<8, 256, 0, stream>>>(w, l2k);
  pack_w_frag<<<128, 256, 0, stream>>>(w, phi, plo);
  argmin_mfma<<<BN_TOT / QB, 256, 0, stream>>>(x, phi, plo, l2k, bidx, flagcnt, flagged);
  fixup_kernel<<<256, 256, 0, stream>>>(x, w, l2k, flagged, flagcnt, bidx);
  epilogue_kernel<<<8192, 256, 0, stream>>>(x, w, bidx, out, part, counts);
  finalize_kernel<<<1, 256, 0, stream>>>(counts, part, out);
}